// Round 8
// baseline (1963.208 us; speedup 1.0000x reference)
//
#include <hip/hip_runtime.h>
#include <cstddef>

namespace {

constexpr int T = 128;

typedef unsigned short u16;
typedef unsigned int u32;
typedef unsigned long long u64;
typedef __attribute__((ext_vector_type(8))) short short8;
typedef __attribute__((ext_vector_type(4))) float f32x4;

__device__ __forceinline__ u16 f2bf(float x) {
  u32 u = __float_as_uint(x);
  u = (u + 0x7FFFu + ((u >> 16) & 1u)) >> 16;
  return (u16)u;
}
__device__ __forceinline__ float bf2f(u16 v) {
  return __uint_as_float(((u32)v) << 16);
}
__device__ __forceinline__ float sigf(float x) {
  x = fminf(fmaxf(x, -30.f), 30.f);
  return 1.f / (1.f + __expf(-x));
}
__device__ __forceinline__ float tanhfast(float x) {
  float ax = fminf(fabsf(x), 15.f);
  float e = __expf(-2.f * ax);
  float t = (1.f - e) / (1.f + e);
  return x < 0.f ? -t : t;
}

// ---- WBF sub-offsets (ushort units) ----
constexpr int O_WIH = 0;            // 2*2048*512
constexpr int O_AW1 = 2097152;      // 512*512
constexpr int O_EM1 = 2359296;      // 128*128
constexpr int O_EM2 = 2375680;      // 64*128
constexpr int O_MLP = 2383872;      // 64*512
constexpr int O_LW1 = 2416640;      // 256*128
constexpr int O_LW2 = 2449408;      // 128*256
constexpr int O_LW3 = 2482176;      // 64*128
constexpr int N_WBF = 2490368;

// ---------------------------------------------------------------------------
// One-time fp32 -> bf16 weight conversion into workspace
// ---------------------------------------------------------------------------
__global__ __launch_bounds__(256)
void k_prep(const float* __restrict__ wih, const float* __restrict__ aw1,
            const float* __restrict__ e1, const float* __restrict__ e2,
            const float* __restrict__ mw, const float* __restrict__ l1,
            const float* __restrict__ l2, const float* __restrict__ l3,
            u16* __restrict__ wbf) {
  int i = blockIdx.x * 256 + threadIdx.x;
  if (i >= N_WBF) return;
  float v;
  if (i < O_AW1)      v = wih[i];
  else if (i < O_EM1) v = aw1[i - O_AW1];
  else if (i < O_EM2) v = e1[i - O_EM1];
  else if (i < O_MLP) v = e2[i - O_EM2];
  else if (i < O_LW1) v = mw[i - O_MLP];
  else if (i < O_LW2) v = l1[i - O_LW1];
  else if (i < O_LW3) v = l2[i - O_LW2];
  else                v = l3[i - O_LW3];
  wbf[i] = f2bf(v);
}

// ---------------------------------------------------------------------------
// xg = X @ Wih_l^T + bih + bhh  via MFMA. Output bf16 packed-pair stores.
// BFIN: input already bf16 (layer 1 reads R0 bf16). grid (256 rowblk, 8 nc)
// ---------------------------------------------------------------------------
template <bool BFIN>
__global__ __launch_bounds__(256)
void k_xg_mfma(const void* __restrict__ Xv, const u16* __restrict__ Wbf,
               const float* __restrict__ bi, const float* __restrict__ bh,
               u16* __restrict__ xg) {
  __shared__ __align__(16) u16 sx[32 * 520];
  int tid = threadIdx.x;
  int rowbase = blockIdx.x * 32;
  int nchunk = blockIdx.y;
  if (BFIN) {
    const u16* X = (const u16*)Xv;
    for (int idx = tid; idx < 2048; idx += 256) {
      int r = idx >> 6, q = idx & 63;
      *(u64*)(sx + r * 520 + q * 8) = *(const u64*)(X + (size_t)(rowbase + r) * 512 + q * 8);
    }
  } else {
    const float* X = (const float*)Xv;
    for (int idx = tid; idx < 4096; idx += 256) {
      int r = idx >> 7, k4 = idx & 127;
      float4 v = *(const float4*)(X + (size_t)(rowbase + r) * 512 + k4 * 4);
      u32* p = (u32*)(sx + r * 520 + k4 * 4);
      p[0] = (u32)f2bf(v.x) | ((u32)f2bf(v.y) << 16);
      p[1] = (u32)f2bf(v.z) | ((u32)f2bf(v.w) << 16);
    }
  }
  __syncthreads();
  int w = tid >> 6, lane = tid & 63;
  int msub = w >> 1, nhalf = w & 1;
  int mbase = msub * 16;
  int nb0 = nchunk * 256 + nhalf * 128;
  f32x4 acc[8];
#pragma unroll
  for (int i = 0; i < 8; ++i) acc[i] = f32x4{0.f, 0.f, 0.f, 0.f};
  for (int kt = 0; kt < 16; ++kt) {
    short8 a = *(const short8*)(sx + (mbase + (lane & 15)) * 520 + kt * 32 + (lane >> 4) * 8);
#pragma unroll
    for (int nt = 0; nt < 8; ++nt) {
      short8 b = *(const short8*)(Wbf + (size_t)(nb0 + nt * 16 + (lane & 15)) * 512 +
                                  kt * 32 + (lane >> 4) * 8);
      acc[nt] = __builtin_amdgcn_mfma_f32_16x16x32_bf16(a, b, acc[nt], 0, 0, 0);
    }
  }
  int mr = mbase + (lane >> 4) * 4;
#pragma unroll
  for (int nt = 0; nt < 8; ++nt) {
    int n = nb0 + nt * 16 + (lane & 15);
    float bb = bi[n] + bh[n];
#pragma unroll
    for (int r = 0; r < 4; ++r) {
      u16 myv = f2bf(acc[nt][r] + bb);
      u16 other = (u16)__shfl_xor((int)myv, 1);
      if ((lane & 1) == 0) {
        u32 word = (u32)myv | ((u32)other << 16);
        *(u32*)(xg + (size_t)(rowbase + mr + r) * 2048 + n) = word;
      }
    }
  }
}

// ---------------------------------------------------------------------------
// MFMA LSTM v4 (proven): 32 blocks = [d:2][j-chunk c:16]. Per-WAVE monotonic
// flags; protocol per step: h-stores -> vmcnt(0) -> flag -> out[] -> xv.
// xg input bf16; out stored bf16 (packed pair words). Agent-scope atomics.
// ---------------------------------------------------------------------------
__global__ __launch_bounds__(256, 1)
void k_lstm4(const u16* __restrict__ xg, const float* __restrict__ whh,
             const int* __restrict__ lens, u16* __restrict__ outb,
             u16* __restrict__ hg, u32* __restrict__ flg, int layer) {
  const int d = blockIdx.x >> 4, c = blockIdx.x & 15;
  const int tid = threadIdx.x;
  const int l = tid & 63;
  const int w = tid >> 6;
  const int ln = l & 15, lk = l >> 4;

  short8 Bf[8][4];
  const float* wbase = whh + (size_t)(layer * 2 + d) * 262144;
#pragma unroll
  for (int kk = 0; kk < 8; ++kk) {
#pragma unroll
    for (int g = 0; g < 4; ++g) {
      const float* rp = wbase + (size_t)(g * 256 + c * 16 + ln) * 256 + kk * 32 + lk * 8;
      float4 lo = *(const float4*)rp;
      float4 hi = *(const float4*)(rp + 4);
      short8 b;
      b[0] = (short)f2bf(lo.x); b[1] = (short)f2bf(lo.y);
      b[2] = (short)f2bf(lo.z); b[3] = (short)f2bf(lo.w);
      b[4] = (short)f2bf(hi.x); b[5] = (short)f2bf(hi.y);
      b[6] = (short)f2bf(hi.z); b[7] = (short)f2bf(hi.w);
      Bf[kk][g] = b;
    }
  }

  u16* hbuf0 = hg + d * 32768;          // parity 0: [64 m][256 j] bf16
  u16* hbuf1 = hbuf0 + 16384;           // parity 1
  u32* fbase = flg + d * 64;
  const int myflag = c * 4 + w;

  const int m0 = w * 16;
  const int j  = c * 16 + ln;
  int mlen[4];
#pragma unroll
  for (int r = 0; r < 4; ++r) mlen[r] = lens[m0 + lk * 4 + r];

  float cst[4], hst[4];
#pragma unroll
  for (int r = 0; r < 4; ++r) { cst[r] = 0.f; hst[r] = 0.f; }

  float xv[4][4];
  {
    int t0 = d ? 127 : 0;
#pragma unroll
    for (int g = 0; g < 4; ++g)
#pragma unroll
      for (int r = 0; r < 4; ++r)
        xv[g][r] = bf2f(xg[((size_t)(m0 + lk * 4 + r) * 128 + t0) * 2048 +
                           d * 1024 + g * 256 + j]);
  }

  for (int s = 0; s < 128; ++s) {
    const int t = d ? (127 - s) : s;

    f32x4 acc[4];
#pragma unroll
    for (int g = 0; g < 4; ++g)
      acc[g] = f32x4{xv[g][0], xv[g][1], xv[g][2], xv[g][3]};

    if (s > 0) {
      const u32 tgt = (u32)(layer * 128 + s);
      for (;;) {
        u32 fv = __hip_atomic_load(fbase + l, __ATOMIC_RELAXED, __HIP_MEMORY_SCOPE_AGENT);
        if (__all(fv >= tgt)) break;
        __builtin_amdgcn_s_sleep(1);
      }
      const u16* hp = ((s - 1) & 1) ? hbuf1 : hbuf0;
#pragma unroll
      for (int kk = 0; kk < 8; ++kk) {
        const u64* p = (const u64*)(hp + (m0 + ln) * 256 + kk * 32 + lk * 8);
        union { u64 q[2]; short8 v; } ua;
        ua.q[0] = __hip_atomic_load(p, __ATOMIC_RELAXED, __HIP_MEMORY_SCOPE_AGENT);
        ua.q[1] = __hip_atomic_load(p + 1, __ATOMIC_RELAXED, __HIP_MEMORY_SCOPE_AGENT);
        short8 a = ua.v;
#pragma unroll
        for (int g = 0; g < 4; ++g)
          acc[g] = __builtin_amdgcn_mfma_f32_16x16x32_bf16(a, Bf[kk][g], acc[g], 0, 0, 0);
      }
    }

    // ---- gates + state update; publish h_s (parity s&1) ----
    u16* hw = (s & 1) ? hbuf1 : hbuf0;
    u32 wword[4];
#pragma unroll
    for (int r = 0; r < 4; ++r) {
      float gi = acc[0][r];
      float gf = acc[1][r];
      float gg = acc[2][r];
      float go = acc[3][r];
      float c2 = sigf(gf) * cst[r] + sigf(gi) * tanhfast(gg);
      float h2 = sigf(go) * tanhfast(c2);
      const int m = m0 + lk * 4 + r;
      bool upd = t < mlen[r];
      cst[r] = upd ? c2 : cst[r];
      float hn = upd ? h2 : hst[r];
      hst[r] = hn;
      u16 myv = f2bf(hn);
      u16 other = (u16)__shfl_xor((int)myv, 1);
      u32 word = (u32)myv | ((u32)other << 16);   // valid on even lanes
      wword[r] = word;
      if ((ln & 1) == 0)
        __hip_atomic_store((u32*)(hw + m * 256 + (j & ~1)), word,
                           __ATOMIC_RELAXED, __HIP_MEMORY_SCOPE_AGENT);
    }

    // drain ONLY the just-issued h stores (out/xv from prev step long done)
    asm volatile("s_waitcnt vmcnt(0)" ::: "memory");

    if (s < 127)
      __hip_atomic_store(fbase + myflag, (u32)(layer * 128 + s + 1),
                         __ATOMIC_RELAXED, __HIP_MEMORY_SCOPE_AGENT);

    // out[] bf16 packed writes AFTER flag: drain in the shadow of next poll
#pragma unroll
    for (int r = 0; r < 4; ++r) {
      if ((ln & 1) == 0) {
        const int m = m0 + lk * 4 + r;
        *(u32*)(outb + ((size_t)m * 128 + t) * 512 + d * 256 + (j & ~1)) = wword[r];
      }
    }

    if (s < 127) {
      const int tn = d ? (127 - (s + 1)) : (s + 1);
#pragma unroll
      for (int g = 0; g < 4; ++g)
#pragma unroll
        for (int r = 0; r < 4; ++r)
          xv[g][r] = bf2f(xg[((size_t)(m0 + lk * 4 + r) * 128 + tn) * 2048 +
                             d * 1024 + g * 256 + j]);
    }
  }
}

// ---------------------------------------------------------------------------
// attn scores via MFMA: sc[m] = w2 . tanh(W1 @ rnn[m] + b1). rnn is bf16.
// ---------------------------------------------------------------------------
__global__ __launch_bounds__(256)
void k_attn(const u16* __restrict__ rnnb, const u16* __restrict__ W1bf,
            const float* __restrict__ b1, const float* __restrict__ w2,
            float* __restrict__ sc) {
  __shared__ __align__(16) u16 sx[32 * 520];
  __shared__ float sred[32];
  int tid = threadIdx.x;
  int rowbase = blockIdx.x * 32;
  for (int idx = tid; idx < 2048; idx += 256) {
    int r = idx >> 6, q = idx & 63;
    *(u64*)(sx + r * 520 + q * 8) =
        *(const u64*)(rnnb + (size_t)(rowbase + r) * 512 + q * 8);
  }
  if (tid < 32) sred[tid] = 0.f;
  __syncthreads();
  int w = tid >> 6, lane = tid & 63;
  int msub = w >> 1, nhalf = w & 1;
  int mbase = msub * 16;
  float psum[4] = {0.f, 0.f, 0.f, 0.f};
  for (int ng = 0; ng < 4; ++ng) {
    f32x4 acc[4];
#pragma unroll
    for (int i = 0; i < 4; ++i) acc[i] = f32x4{0.f, 0.f, 0.f, 0.f};
    for (int kt = 0; kt < 16; ++kt) {
      short8 a = *(const short8*)(sx + (mbase + (lane & 15)) * 520 + kt * 32 + (lane >> 4) * 8);
#pragma unroll
      for (int nt = 0; nt < 4; ++nt) {
        int nrow = nhalf * 256 + ng * 64 + nt * 16 + (lane & 15);
        short8 b = *(const short8*)(W1bf + (size_t)nrow * 512 + kt * 32 + (lane >> 4) * 8);
        acc[nt] = __builtin_amdgcn_mfma_f32_16x16x32_bf16(a, b, acc[nt], 0, 0, 0);
      }
    }
#pragma unroll
    for (int nt = 0; nt < 4; ++nt) {
      int n = nhalf * 256 + ng * 64 + nt * 16 + (lane & 15);
      float wn = w2[n], bn = b1[n];
#pragma unroll
      for (int r = 0; r < 4; ++r) psum[r] += wn * tanhf(acc[nt][r] + bn);
    }
  }
#pragma unroll
  for (int off = 8; off >= 1; off >>= 1)
#pragma unroll
    for (int r = 0; r < 4; ++r) psum[r] += __shfl_xor(psum[r], off);
  if ((lane & 15) == 0) {
#pragma unroll
    for (int r = 0; r < 4; ++r)
      atomicAdd(&sred[msub * 16 + (lane >> 4) * 4 + r], psum[r]);
  }
  __syncthreads();
  if (tid < 32) sc[rowbase + tid] = sred[tid];
}

// ---------------------------------------------------------------------------
// Causal softmax + weighted sum as prefix scan. rnn bf16. (64 b, 4 hc) x 128
// ---------------------------------------------------------------------------
__global__ __launch_bounds__(128)
void k_ctx(const float* __restrict__ sc, const u16* __restrict__ rnnb,
           const int* __restrict__ lens, float* __restrict__ ctx) {
  int b = blockIdx.x;
  int h = blockIdx.y * 128 + threadIdx.x;
  __shared__ float ex[T];
  ex[threadIdx.x] = expf(sc[b * T + threadIdx.x]);
  __syncthreads();
  int len = lens[b];
  float acc = 0.f, den = 0.f;
  for (int t = 0; t < T; ++t) {
    float wv = ex[t];
    den += wv;
    acc += wv * bf2f(rnnb[((size_t)b * T + t) * 512 + h]);
    ctx[((size_t)b * T + t) * 512 + h] = (t < len) ? (acc / den) : 0.f;
  }
}

// ---------------------------------------------------------------------------
// MFMA MLP stage on a 32-row bf16 LDS tile
// ---------------------------------------------------------------------------
template <int NT, int KT, bool RELU>
__device__ __forceinline__ void stage_mfma(const u16* __restrict__ Wbf,
                                           const float* __restrict__ bias,
                                           const u16* A, int lda,
                                           u16* O, int ldo, int nofs,
                                           int lane, int msub, int nhalf) {
  f32x4 acc[NT];
#pragma unroll
  for (int i = 0; i < NT; ++i) acc[i] = f32x4{0.f, 0.f, 0.f, 0.f};
  int mbase = msub * 16;
  int nb0 = nhalf * (NT * 16);
#pragma unroll
  for (int kt = 0; kt < KT; ++kt) {
    short8 a = *(const short8*)(A + (mbase + (lane & 15)) * lda + kt * 32 + (lane >> 4) * 8);
#pragma unroll
    for (int nt = 0; nt < NT; ++nt) {
      short8 b = *(const short8*)(Wbf + (size_t)(nb0 + nt * 16 + (lane & 15)) * (KT * 32) +
                                  kt * 32 + (lane >> 4) * 8);
      acc[nt] = __builtin_amdgcn_mfma_f32_16x16x32_bf16(a, b, acc[nt], 0, 0, 0);
    }
  }
  int mr = mbase + (lane >> 4) * 4;
#pragma unroll
  for (int nt = 0; nt < NT; ++nt) {
    int nl = nb0 + nt * 16 + (lane & 15);
    float bv = bias[nl];
#pragma unroll
    for (int r = 0; r < 4; ++r) {
      float v = acc[nt][r] + bv;
      if (RELU) v = fmaxf(v, 0.f);
      O[(mr + r) * ldo + nofs + nl] = f2bf(v);
    }
  }
}

// ---------------------------------------------------------------------------
// Fused sample branch, MFMA everywhere. 2 passes x 32 rows/block, 2048 blks.
// Second pass reuses weights from L1/L2 (halves weight restreaming).
// ---------------------------------------------------------------------------
__global__ __launch_bounds__(256)
void k_sample(const float* __restrict__ ctx, const float* __restrict__ d2v,
              const float* __restrict__ user_table, const float* __restrict__ art_table,
              const int* __restrict__ user_ids, const int* __restrict__ sample_ids,
              const u16* __restrict__ wbf,
              const float* __restrict__ em_b1, const float* __restrict__ em_b2,
              const float* __restrict__ mlp_b,
              const float* __restrict__ lm_b1, const float* __restrict__ lm_b2,
              const float* __restrict__ lm_b3,
              const float* __restrict__ lm_W4, const float* __restrict__ lm_b4,
              float* __restrict__ out) {
  __shared__ __align__(16) u16 bufA[32 * 520];
  __shared__ __align__(16) u16 bufB[32 * 264];
  __shared__ __align__(16) u16 bufC[32 * 136];
  int tid = threadIdx.x, lane = tid & 63, w = tid >> 6;
  int msub = w >> 1, nhalf = w & 1;

  for (int pass = 0; pass < 2; ++pass) {
    int rowbase = blockIdx.x * 64 + pass * 32;

    for (int idx = tid; idx < 1024; idx += 256) {
      int r = idx >> 5, k4 = idx & 31;
      int m = rowbase + r;
      int sid = sample_ids[m];
      int uid = user_ids[m >> 11];
      float4 u = *(const float4*)(user_table + (size_t)uid * 128 + k4 * 4);
      float4 a = *(const float4*)(art_table + (size_t)sid * 128 + k4 * 4);
      u32* p = (u32*)(bufA + r * 520 + k4 * 4);
      p[0] = (u32)f2bf(u.x * a.x) | ((u32)f2bf(u.y * a.y) << 16);
      p[1] = (u32)f2bf(u.z * a.z) | ((u32)f2bf(u.w * a.w) << 16);
    }
    __syncthreads();
    stage_mfma<4, 4, true>(wbf + O_EM1, em_b1, bufA, 520, bufB, 264, 0, lane, msub, nhalf);
    __syncthreads();
    stage_mfma<2, 4, true>(wbf + O_EM2, em_b2, bufB, 264, bufC, 136, 0, lane, msub, nhalf);
    for (int idx = tid; idx < 4096; idx += 256) {
      int r = idx >> 7, k4 = idx & 127;
      int m = rowbase + r;
      int bt = m >> 4;
      float4 cx = *(const float4*)(ctx + (size_t)bt * 512 + k4 * 4);
      float4 dv = *(const float4*)(d2v + (size_t)m * 512 + k4 * 4);
      u32* p = (u32*)(bufA + r * 520 + k4 * 4);
      p[0] = (u32)f2bf(cx.x * dv.x) | ((u32)f2bf(cx.y * dv.y) << 16);
      p[1] = (u32)f2bf(cx.z * dv.z) | ((u32)f2bf(cx.w * dv.w) << 16);
    }
    __syncthreads();
    stage_mfma<2, 16, false>(wbf + O_MLP, mlp_b, bufA, 520, bufC, 136, 64, lane, msub, nhalf);
    __syncthreads();
    stage_mfma<8, 4, true>(wbf + O_LW1, lm_b1, bufC, 136, bufB, 264, 0, lane, msub, nhalf);
    __syncthreads();
    stage_mfma<4, 8, true>(wbf + O_LW2, lm_b2, bufB, 264, bufA, 520, 0, lane, msub, nhalf);
    __syncthreads();
    stage_mfma<2, 4, true>(wbf + O_LW3, lm_b3, bufA, 520, bufC, 136, 0, lane, msub, nhalf);
    __syncthreads();

    if (tid < 32) {
      float acc = lm_b4[0];
#pragma unroll
      for (int k = 0; k < 64; ++k) acc += bf2f(bufC[tid * 136 + k]) * lm_W4[k];
      out[rowbase + tid] = 1.f / (1.f + expf(-acc));
    }
  }
}

}  // namespace

extern "C" void kernel_launch(void* const* d_in, const int* in_sizes, int n_in,
                              void* d_out, int out_size, void* d_ws, size_t ws_size,
                              hipStream_t stream) {
  const float* x1   = (const float*)d_in[0];
  const float* d2v  = (const float*)d_in[1];
  const float* Wih  = (const float*)d_in[2];
  const float* Whh  = (const float*)d_in[3];
  const float* bih  = (const float*)d_in[4];
  const float* bhh  = (const float*)d_in[5];
  const float* aW1  = (const float*)d_in[6];
  const float* ab1  = (const float*)d_in[7];
  const float* aw2  = (const float*)d_in[8];
  const float* mlpW = (const float*)d_in[9];
  const float* mlpb = (const float*)d_in[10];
  const float* utab = (const float*)d_in[11];
  const float* atab = (const float*)d_in[12];
  const float* emW1 = (const float*)d_in[13];
  const float* emb1 = (const float*)d_in[14];
  const float* emW2 = (const float*)d_in[15];
  const float* emb2 = (const float*)d_in[16];
  const float* lmW1 = (const float*)d_in[17];
  const float* lmb1 = (const float*)d_in[18];
  const float* lmW2 = (const float*)d_in[19];
  const float* lmb2 = (const float*)d_in[20];
  const float* lmW3 = (const float*)d_in[21];
  const float* lmb3 = (const float*)d_in[22];
  const float* lmW4 = (const float*)d_in[23];
  const float* lmb4 = (const float*)d_in[24];
  const int* lens   = (const int*)d_in[27];
  const int* uids   = (const int*)d_in[28];
  const int* sids   = (const int*)d_in[29];
  float* out = (float*)d_out;

  float* ws = (float*)d_ws;
  // float-unit offsets
  u32* FLG = (u32*)ws;                                 // 128 u32   [0, 128)
  u16* HG  = (u16*)(ws + 128);                         // 65536 u16 [128, 32896)
  float* SC  = ws + 32896;                             // 8192
  u16* WBF = (u16*)(ws + 41088);                       // 2,490,368 u16
  u16* XG  = (u16*)(ws + 1286272);                     // 16,777,216 u16
  u16* R0  = (u16*)(ws + 9674880);                     // 4,194,304 u16
  u16* R1  = (u16*)(ws + 11772032);                    // 4,194,304 u16
  float* CTX = ws + 13869184;                          // 4,194,304 f32

  hipMemsetAsync(FLG, 0, 512, stream);
  k_prep<<<(N_WBF + 255) / 256, 256, 0, stream>>>(Wih, aW1, emW1, emW2, mlpW,
                                                  lmW1, lmW2, lmW3, WBF);
  k_xg_mfma<false><<<dim3(256, 8), 256, 0, stream>>>(x1, WBF + O_WIH, bih, bhh, XG);
  k_lstm4<<<32, 256, 0, stream>>>(XG, Whh, lens, R0, HG, FLG, 0);
  k_xg_mfma<true><<<dim3(256, 8), 256, 0, stream>>>(R0, WBF + O_WIH + 1048576,
                                                    bih + 2048, bhh + 2048, XG);
  k_lstm4<<<32, 256, 0, stream>>>(XG, Whh, lens, R1, HG, FLG, 1);
  k_attn<<<256, 256, 0, stream>>>(R1, WBF + O_AW1, ab1, aw2, SC);
  k_ctx<<<dim3(64, 4), 128, 0, stream>>>(SC, R1, lens, CTX);
  k_sample<<<2048, 256, 0, stream>>>(CTX, d2v, utab, atab, uids, sids, WBF,
                                     emb1, emb2, mlpb, lmb1, lmb2, lmb3,
                                     lmW4, lmb4, out);
}

// Round 9
// 1602.090 us; speedup vs baseline: 1.2254x; 1.2254x over previous
//
#include <hip/hip_runtime.h>
#include <cstddef>

namespace {

constexpr int T = 128;

typedef unsigned short u16;
typedef unsigned int u32;
typedef __attribute__((ext_vector_type(8))) short short8;
typedef __attribute__((ext_vector_type(4))) float f32x4;
typedef __attribute__((ext_vector_type(4))) int i32x4;

__device__ __forceinline__ u16 f2bf(float x) {
  u32 u = __float_as_uint(x);
  u = (u + 0x7FFFu + ((u >> 16) & 1u)) >> 16;
  return (u16)u;
}
__device__ __forceinline__ float bf2f(u16 v) {
  return __uint_as_float(((u32)v) << 16);
}
__device__ __forceinline__ float sigf(float x) {
  x = fminf(fmaxf(x, -30.f), 30.f);
  return 1.f / (1.f + __expf(-x));
}
__device__ __forceinline__ float tanhfast(float x) {
  float ax = fminf(fabsf(x), 15.f);
  float e = __expf(-2.f * ax);
  float t = (1.f - e) / (1.f + e);
  return x < 0.f ? -t : t;
}

// ---- WBF sub-offsets (ushort units) ----
constexpr int O_WIH = 0;            // 2*2048*512
constexpr int O_AW1 = 2097152;      // 512*512
constexpr int O_EM1 = 2359296;      // 128*128
constexpr int O_EM2 = 2375680;      // 64*128
constexpr int O_MLP = 2383872;      // 64*512
constexpr int O_LW1 = 2416640;      // 256*128
constexpr int O_LW2 = 2449408;      // 128*256
constexpr int O_LW3 = 2482176;      // 64*128
constexpr int N_WBF = 2490368;

// ---------------------------------------------------------------------------
// One-time fp32 -> bf16 weight conversion into workspace
// ---------------------------------------------------------------------------
__global__ __launch_bounds__(256)
void k_prep(const float* __restrict__ wih, const float* __restrict__ aw1,
            const float* __restrict__ e1, const float* __restrict__ e2,
            const float* __restrict__ mw, const float* __restrict__ l1,
            const float* __restrict__ l2, const float* __restrict__ l3,
            u16* __restrict__ wbf) {
  int i = blockIdx.x * 256 + threadIdx.x;
  if (i >= N_WBF) return;
  float v;
  if (i < O_AW1)      v = wih[i];
  else if (i < O_EM1) v = aw1[i - O_AW1];
  else if (i < O_EM2) v = e1[i - O_EM1];
  else if (i < O_MLP) v = e2[i - O_EM2];
  else if (i < O_LW1) v = mw[i - O_MLP];
  else if (i < O_LW2) v = l1[i - O_LW1];
  else if (i < O_LW3) v = l2[i - O_LW2];
  else                v = l3[i - O_LW3];
  wbf[i] = f2bf(v);
}

// ---------------------------------------------------------------------------
// Whh fp32 -> i8 (scale 1016 = 127/0.125; |w|max ~0.097, no clipping)
// ---------------------------------------------------------------------------
__global__ __launch_bounds__(256)
void k_prepw(const float* __restrict__ whh, signed char* __restrict__ wq) {
  int i = blockIdx.x * 256 + threadIdx.x;   // 1,048,576 total
  float v = whh[i] * 1016.f;
  v = fminf(fmaxf(v, -127.f), 127.f);
  wq[i] = (signed char)(int)rintf(v);
}

// ---------------------------------------------------------------------------
// xg = X @ Wih_l^T + bih + bhh   via MFMA.  grid (256 rowblk, 8 nchunk)
// ---------------------------------------------------------------------------
__global__ __launch_bounds__(256)
void k_xg_mfma(const float* __restrict__ X, const u16* __restrict__ Wbf,
               const float* __restrict__ bi, const float* __restrict__ bh,
               float* __restrict__ xg) {
  __shared__ __align__(16) u16 sx[32 * 520];
  int tid = threadIdx.x;
  int rowbase = blockIdx.x * 32;
  int nchunk = blockIdx.y;
  for (int idx = tid; idx < 4096; idx += 256) {
    int r = idx >> 7, k4 = idx & 127;
    float4 v = *(const float4*)(X + (size_t)(rowbase + r) * 512 + k4 * 4);
    u32* p = (u32*)(sx + r * 520 + k4 * 4);
    p[0] = (u32)f2bf(v.x) | ((u32)f2bf(v.y) << 16);
    p[1] = (u32)f2bf(v.z) | ((u32)f2bf(v.w) << 16);
  }
  __syncthreads();
  int w = tid >> 6, lane = tid & 63;
  int msub = w >> 1, nhalf = w & 1;
  int mbase = msub * 16;
  int nb0 = nchunk * 256 + nhalf * 128;
  f32x4 acc[8];
#pragma unroll
  for (int i = 0; i < 8; ++i) acc[i] = f32x4{0.f, 0.f, 0.f, 0.f};
  for (int kt = 0; kt < 16; ++kt) {
    short8 a = *(const short8*)(sx + (mbase + (lane & 15)) * 520 + kt * 32 + (lane >> 4) * 8);
#pragma unroll
    for (int nt = 0; nt < 8; ++nt) {
      short8 b = *(const short8*)(Wbf + (size_t)(nb0 + nt * 16 + (lane & 15)) * 512 +
                                  kt * 32 + (lane >> 4) * 8);
      acc[nt] = __builtin_amdgcn_mfma_f32_16x16x32_bf16(a, b, acc[nt], 0, 0, 0);
    }
  }
  int mr = mbase + (lane >> 4) * 4;
#pragma unroll
  for (int nt = 0; nt < 8; ++nt) {
    int n = nb0 + nt * 16 + (lane & 15);
    float bb = bi[n] + bh[n];
#pragma unroll
    for (int r = 0; r < 4; ++r)
      xg[(size_t)(rowbase + mr + r) * 2048 + n] = acc[nt][r] + bb;
  }
}

// ---------------------------------------------------------------------------
// MFMA LSTM v7: batch-split, ZERO inter-block sync. 8 blocks = [d:2][bg:4],
// 512 threads. Full-direction Whh i8 in registers (32 frags = 128 VGPR).
// h in block-local LDS (i8, 272B row stride), one barrier per step.
// Wave jc owns hidden cols j in [jc*32, jc*32+32) for ALL 4 gates, so the
// i,f,g,o values of a (m,j) pair land in the same lane (pure-reg combine).
// mfma_i32_16x16x64_i8: A[m=ln][k=lk*16+f], B[k][n=ln], D[m=lk*4+r][n=ln].
// ---------------------------------------------------------------------------
__global__ __launch_bounds__(512, 1)
void k_lstm6(const float* __restrict__ xg, const signed char* __restrict__ wq,
             const int* __restrict__ lens, float* __restrict__ out, int layer) {
  __shared__ __align__(16) signed char hq[2][16 * 272];
  const int d = blockIdx.x >> 2, bg = blockIdx.x & 3;
  const int tid = threadIdx.x;
  const int jc = tid >> 6, l = tid & 63, ln = l & 15, lk = l >> 4;
  const int mb = bg * 16;

  // ---- weights: full direction, i8, register-resident ----
  i32x4 Bq[4][2][4];
  const signed char* wbase = wq + (size_t)(layer * 2 + d) * 262144;
#pragma unroll
  for (int g = 0; g < 4; ++g)
#pragma unroll
    for (int js = 0; js < 2; ++js)
#pragma unroll
      for (int kc = 0; kc < 4; ++kc) {
        int n = g * 256 + jc * 32 + js * 16 + ln;
        Bq[g][js][kc] = *(const i32x4*)(wbase + (size_t)n * 256 + kc * 64 + lk * 16);
      }

  int mlen[4];
#pragma unroll
  for (int r = 0; r < 4; ++r) mlen[r] = lens[mb + lk * 4 + r];

  float cst[2][4], hst[2][4];
#pragma unroll
  for (int js = 0; js < 2; ++js)
#pragma unroll
    for (int r = 0; r < 4; ++r) { cst[js][r] = 0.f; hst[js][r] = 0.f; }

  const float DEQ = 1.f / (1016.f * 127.f);

  for (int s = 0; s < 128; ++s) {
    const int t = d ? (127 - s) : s;

    // xg pre-activations: issued first, consumed after MFMA (latency hidden)
    float xv[4][2][4];
#pragma unroll
    for (int g = 0; g < 4; ++g)
#pragma unroll
      for (int js = 0; js < 2; ++js)
#pragma unroll
        for (int r = 0; r < 4; ++r)
          xv[g][js][r] = xg[((size_t)(mb + lk * 4 + r) * 128 + t) * 2048 +
                            d * 1024 + g * 256 + jc * 32 + js * 16 + ln];

    i32x4 acc[4][2];
#pragma unroll
    for (int g = 0; g < 4; ++g)
#pragma unroll
      for (int js = 0; js < 2; ++js) acc[g][js] = i32x4{0, 0, 0, 0};

    if (s > 0) {
      const signed char* hr = hq[(s & 1) ^ 1];
#pragma unroll
      for (int kc = 0; kc < 4; ++kc) {
        i32x4 a = *(const i32x4*)(hr + ln * 272 + kc * 64 + lk * 16);
#pragma unroll
        for (int g = 0; g < 4; ++g)
#pragma unroll
          for (int js = 0; js < 2; ++js)
            acc[g][js] = __builtin_amdgcn_mfma_i32_16x16x64_i8(a, Bq[g][js][kc],
                                                               acc[g][js], 0, 0, 0);
      }
    }

    signed char* hw = hq[s & 1];
#pragma unroll
    for (int js = 0; js < 2; ++js)
#pragma unroll
      for (int r = 0; r < 4; ++r) {
        float gi = (float)acc[0][js][r] * DEQ + xv[0][js][r];
        float gf = (float)acc[1][js][r] * DEQ + xv[1][js][r];
        float gg = (float)acc[2][js][r] * DEQ + xv[2][js][r];
        float go = (float)acc[3][js][r] * DEQ + xv[3][js][r];
        float c2 = sigf(gf) * cst[js][r] + sigf(gi) * tanhfast(gg);
        float h2 = sigf(go) * tanhfast(c2);
        const int m = lk * 4 + r;
        bool upd = t < mlen[r];
        cst[js][r] = upd ? c2 : cst[js][r];
        float hn = upd ? h2 : hst[js][r];
        hst[js][r] = hn;
        const int j = jc * 32 + js * 16 + ln;
        out[((size_t)(mb + m) * 128 + t) * 512 + d * 256 + j] = hn;
        hw[m * 272 + j] = (signed char)(int)rintf(hn * 127.f);
      }
    __syncthreads();
  }
}

// ---------------------------------------------------------------------------
// attn scores via MFMA: sc[m] = w2 . tanh(W1 @ rnn[m] + b1)
// ---------------------------------------------------------------------------
__global__ __launch_bounds__(256)
void k_attn(const float* __restrict__ rnn, const u16* __restrict__ W1bf,
            const float* __restrict__ b1, const float* __restrict__ w2,
            float* __restrict__ sc) {
  __shared__ __align__(16) u16 sx[32 * 520];
  __shared__ float sred[32];
  int tid = threadIdx.x;
  int rowbase = blockIdx.x * 32;
  for (int idx = tid; idx < 4096; idx += 256) {
    int r = idx >> 7, k4 = idx & 127;
    float4 v = *(const float4*)(rnn + (size_t)(rowbase + r) * 512 + k4 * 4);
    u32* p = (u32*)(sx + r * 520 + k4 * 4);
    p[0] = (u32)f2bf(v.x) | ((u32)f2bf(v.y) << 16);
    p[1] = (u32)f2bf(v.z) | ((u32)f2bf(v.w) << 16);
  }
  if (tid < 32) sred[tid] = 0.f;
  __syncthreads();
  int w = tid >> 6, lane = tid & 63;
  int msub = w >> 1, nhalf = w & 1;
  int mbase = msub * 16;
  float psum[4] = {0.f, 0.f, 0.f, 0.f};
  for (int ng = 0; ng < 4; ++ng) {
    f32x4 acc[4];
#pragma unroll
    for (int i = 0; i < 4; ++i) acc[i] = f32x4{0.f, 0.f, 0.f, 0.f};
    for (int kt = 0; kt < 16; ++kt) {
      short8 a = *(const short8*)(sx + (mbase + (lane & 15)) * 520 + kt * 32 + (lane >> 4) * 8);
#pragma unroll
      for (int nt = 0; nt < 4; ++nt) {
        int nrow = nhalf * 256 + ng * 64 + nt * 16 + (lane & 15);
        short8 b = *(const short8*)(W1bf + (size_t)nrow * 512 + kt * 32 + (lane >> 4) * 8);
        acc[nt] = __builtin_amdgcn_mfma_f32_16x16x32_bf16(a, b, acc[nt], 0, 0, 0);
      }
    }
#pragma unroll
    for (int nt = 0; nt < 4; ++nt) {
      int n = nhalf * 256 + ng * 64 + nt * 16 + (lane & 15);
      float wn = w2[n], bn = b1[n];
#pragma unroll
      for (int r = 0; r < 4; ++r) psum[r] += wn * tanhf(acc[nt][r] + bn);
    }
  }
#pragma unroll
  for (int off = 8; off >= 1; off >>= 1)
#pragma unroll
    for (int r = 0; r < 4; ++r) psum[r] += __shfl_xor(psum[r], off);
  if ((lane & 15) == 0) {
#pragma unroll
    for (int r = 0; r < 4; ++r)
      atomicAdd(&sred[msub * 16 + (lane >> 4) * 4 + r], psum[r]);
  }
  __syncthreads();
  if (tid < 32) sc[rowbase + tid] = sred[tid];
}

// ---------------------------------------------------------------------------
// Causal softmax + weighted sum as prefix scan. grid (64 b, 4 hchunk) x 128.
// ---------------------------------------------------------------------------
__global__ __launch_bounds__(128)
void k_ctx(const float* __restrict__ sc, const float* __restrict__ rnn,
           const int* __restrict__ lens, float* __restrict__ ctx) {
  int b = blockIdx.x;
  int h = blockIdx.y * 128 + threadIdx.x;
  __shared__ float ex[T];
  ex[threadIdx.x] = expf(sc[b * T + threadIdx.x]);
  __syncthreads();
  int len = lens[b];
  float acc = 0.f, den = 0.f;
  for (int t = 0; t < T; ++t) {
    float wv = ex[t];
    den += wv;
    acc += wv * rnn[((size_t)b * T + t) * 512 + h];
    ctx[((size_t)b * T + t) * 512 + h] = (t < len) ? (acc / den) : 0.f;
  }
}

// ---------------------------------------------------------------------------
// MFMA MLP stage on a 32-row bf16 LDS tile
// ---------------------------------------------------------------------------
template <int NT, int KT, bool RELU>
__device__ __forceinline__ void stage_mfma(const u16* __restrict__ Wbf,
                                           const float* __restrict__ bias,
                                           const u16* A, int lda,
                                           u16* O, int ldo, int nofs,
                                           int lane, int msub, int nhalf) {
  f32x4 acc[NT];
#pragma unroll
  for (int i = 0; i < NT; ++i) acc[i] = f32x4{0.f, 0.f, 0.f, 0.f};
  int mbase = msub * 16;
  int nb0 = nhalf * (NT * 16);
#pragma unroll
  for (int kt = 0; kt < KT; ++kt) {
    short8 a = *(const short8*)(A + (mbase + (lane & 15)) * lda + kt * 32 + (lane >> 4) * 8);
#pragma unroll
    for (int nt = 0; nt < NT; ++nt) {
      short8 b = *(const short8*)(Wbf + (size_t)(nb0 + nt * 16 + (lane & 15)) * (KT * 32) +
                                  kt * 32 + (lane >> 4) * 8);
      acc[nt] = __builtin_amdgcn_mfma_f32_16x16x32_bf16(a, b, acc[nt], 0, 0, 0);
    }
  }
  int mr = mbase + (lane >> 4) * 4;
#pragma unroll
  for (int nt = 0; nt < NT; ++nt) {
    int nl = nb0 + nt * 16 + (lane & 15);
    float bv = bias[nl];
#pragma unroll
    for (int r = 0; r < 4; ++r) {
      float v = acc[nt][r] + bv;
      if (RELU) v = fmaxf(v, 0.f);
      O[(mr + r) * ldo + nofs + nl] = f2bf(v);
    }
  }
}

// ---------------------------------------------------------------------------
// Fused sample branch, MFMA everywhere. 32 rows/block, 4096 blocks.
// ---------------------------------------------------------------------------
__global__ __launch_bounds__(256)
void k_sample(const float* __restrict__ ctx, const float* __restrict__ d2v,
              const float* __restrict__ user_table, const float* __restrict__ art_table,
              const int* __restrict__ user_ids, const int* __restrict__ sample_ids,
              const u16* __restrict__ wbf,
              const float* __restrict__ em_b1, const float* __restrict__ em_b2,
              const float* __restrict__ mlp_b,
              const float* __restrict__ lm_b1, const float* __restrict__ lm_b2,
              const float* __restrict__ lm_b3,
              const float* __restrict__ lm_W4, const float* __restrict__ lm_b4,
              float* __restrict__ out) {
  __shared__ __align__(16) u16 bufA[32 * 520];
  __shared__ __align__(16) u16 bufB[32 * 264];
  __shared__ __align__(16) u16 bufC[32 * 136];
  int tid = threadIdx.x, lane = tid & 63, w = tid >> 6;
  int msub = w >> 1, nhalf = w & 1;
  int rowbase = blockIdx.x * 32;

  for (int idx = tid; idx < 1024; idx += 256) {
    int r = idx >> 5, k4 = idx & 31;
    int m = rowbase + r;
    int sid = sample_ids[m];
    int uid = user_ids[m >> 11];
    float4 u = *(const float4*)(user_table + (size_t)uid * 128 + k4 * 4);
    float4 a = *(const float4*)(art_table + (size_t)sid * 128 + k4 * 4);
    u32* p = (u32*)(bufA + r * 520 + k4 * 4);
    p[0] = (u32)f2bf(u.x * a.x) | ((u32)f2bf(u.y * a.y) << 16);
    p[1] = (u32)f2bf(u.z * a.z) | ((u32)f2bf(u.w * a.w) << 16);
  }
  __syncthreads();
  stage_mfma<4, 4, true>(wbf + O_EM1, em_b1, bufA, 520, bufB, 264, 0, lane, msub, nhalf);
  __syncthreads();
  stage_mfma<2, 4, true>(wbf + O_EM2, em_b2, bufB, 264, bufC, 136, 0, lane, msub, nhalf);
  for (int idx = tid; idx < 4096; idx += 256) {
    int r = idx >> 7, k4 = idx & 127;
    int m = rowbase + r;
    int bt = m >> 4;
    float4 cx = *(const float4*)(ctx + (size_t)bt * 512 + k4 * 4);
    float4 dv = *(const float4*)(d2v + (size_t)m * 512 + k4 * 4);
    u32* p = (u32*)(bufA + r * 520 + k4 * 4);
    p[0] = (u32)f2bf(cx.x * dv.x) | ((u32)f2bf(cx.y * dv.y) << 16);
    p[1] = (u32)f2bf(cx.z * dv.z) | ((u32)f2bf(cx.w * dv.w) << 16);
  }
  __syncthreads();
  stage_mfma<2, 16, false>(wbf + O_MLP, mlp_b, bufA, 520, bufC, 136, 64, lane, msub, nhalf);
  __syncthreads();
  stage_mfma<8, 4, true>(wbf + O_LW1, lm_b1, bufC, 136, bufB, 264, 0, lane, msub, nhalf);
  __syncthreads();
  stage_mfma<4, 8, true>(wbf + O_LW2, lm_b2, bufB, 264, bufA, 520, 0, lane, msub, nhalf);
  __syncthreads();
  stage_mfma<2, 4, true>(wbf + O_LW3, lm_b3, bufA, 520, bufC, 136, 0, lane, msub, nhalf);
  __syncthreads();

  if (tid < 32) {
    float acc = lm_b4[0];
#pragma unroll
    for (int k = 0; k < 64; ++k) acc += bf2f(bufC[tid * 136 + k]) * lm_W4[k];
    out[rowbase + tid] = 1.f / (1.f + expf(-acc));
  }
}

}  // namespace

extern "C" void kernel_launch(void* const* d_in, const int* in_sizes, int n_in,
                              void* d_out, int out_size, void* d_ws, size_t ws_size,
                              hipStream_t stream) {
  const float* x1   = (const float*)d_in[0];
  const float* d2v  = (const float*)d_in[1];
  const float* Wih  = (const float*)d_in[2];
  const float* Whh  = (const float*)d_in[3];
  const float* bih  = (const float*)d_in[4];
  const float* bhh  = (const float*)d_in[5];
  const float* aW1  = (const float*)d_in[6];
  const float* ab1  = (const float*)d_in[7];
  const float* aw2  = (const float*)d_in[8];
  const float* mlpW = (const float*)d_in[9];
  const float* mlpb = (const float*)d_in[10];
  const float* utab = (const float*)d_in[11];
  const float* atab = (const float*)d_in[12];
  const float* emW1 = (const float*)d_in[13];
  const float* emb1 = (const float*)d_in[14];
  const float* emW2 = (const float*)d_in[15];
  const float* emb2 = (const float*)d_in[16];
  const float* lmW1 = (const float*)d_in[17];
  const float* lmb1 = (const float*)d_in[18];
  const float* lmW2 = (const float*)d_in[19];
  const float* lmb2 = (const float*)d_in[20];
  const float* lmW3 = (const float*)d_in[21];
  const float* lmb3 = (const float*)d_in[22];
  const float* lmW4 = (const float*)d_in[23];
  const float* lmb4 = (const float*)d_in[24];
  const int* lens   = (const int*)d_in[27];
  const int* uids   = (const int*)d_in[28];
  const int* sids   = (const int*)d_in[29];
  float* out = (float*)d_out;

  float* ws = (float*)d_ws;
  // float-unit offsets
  signed char* WQ = (signed char*)ws;                  // 1 MB i8 [0, 262144)
  float* SC  = ws + 262144;                            // 8192
  u16* WBF = (u16*)(ws + 270336);                      // 2,490,368 u16
  float* XG  = ws + 1515520;                           // 16,777,216 f32
  float* R0  = ws + 18292736;                          // 4,194,304
  float* R1  = ws + 22487040;                          // 4,194,304
  float* CTX = ws + 18292736;                          // overlays R0 (R0 dead
                                                       // before k_ctx writes)

  k_prep<<<(N_WBF + 255) / 256, 256, 0, stream>>>(Wih, aW1, emW1, emW2, mlpW,
                                                  lmW1, lmW2, lmW3, WBF);
  k_prepw<<<4096, 256, 0, stream>>>(Whh, WQ);
  k_xg_mfma<<<dim3(256, 8), 256, 0, stream>>>(x1, WBF + O_WIH, bih, bhh, XG);
  k_lstm6<<<8, 512, 0, stream>>>(XG, WQ, lens, R0, 0);
  k_xg_mfma<<<dim3(256, 8), 256, 0, stream>>>(R0, WBF + O_WIH + 1048576,
                                              bih + 2048, bhh + 2048, XG);
  k_lstm6<<<8, 512, 0, stream>>>(XG, WQ, lens, R1, 1);
  k_attn<<<256, 256, 0, stream>>>(R1, WBF + O_AW1, ab1, aw2, SC);
  k_ctx<<<dim3(64, 4), 128, 0, stream>>>(SC, R1, lens, CTX);
  k_sample<<<4096, 256, 0, stream>>>(CTX, d2v, utab, atab, uids, sids, WBF,
                                     emb1, emb2, mlpb, lmb1, lmb2, lmb3,
                                     lmW4, lmb4, out);
}

// Round 10
// 1267.207 us; speedup vs baseline: 1.5492x; 1.2643x over previous
//
#include <hip/hip_runtime.h>
#include <cstddef>

namespace {

constexpr int T = 128;

typedef unsigned short u16;
typedef unsigned int u32;
typedef __attribute__((ext_vector_type(8))) short short8;
typedef __attribute__((ext_vector_type(4))) float f32x4;
typedef __attribute__((ext_vector_type(4))) int i32x4;

__device__ __forceinline__ u16 f2bf(float x) {
  u32 u = __float_as_uint(x);
  u = (u + 0x7FFFu + ((u >> 16) & 1u)) >> 16;
  return (u16)u;
}
__device__ __forceinline__ float bf2f(u16 v) {
  return __uint_as_float(((u32)v) << 16);
}
// exp2/rcp-based activations: single v_exp_f32 / v_rcp_f32, branch-free,
// correct limits at +-inf (no clamps needed).
__device__ __forceinline__ float sigf(float x) {
  return __builtin_amdgcn_rcpf(1.f + __builtin_amdgcn_exp2f(-1.44269504f * x));
}
__device__ __forceinline__ float tanh2(float x) {
  return 1.f - 2.f * __builtin_amdgcn_rcpf(1.f + __builtin_amdgcn_exp2f(2.88539008f * x));
}

// ---- WBF sub-offsets (ushort units) ----
constexpr int O_WIH = 0;            // 2*2048*512
constexpr int O_AW1 = 2097152;      // 512*512
constexpr int O_EM1 = 2359296;      // 128*128
constexpr int O_EM2 = 2375680;      // 64*128
constexpr int O_MLP = 2383872;      // 64*512
constexpr int O_LW1 = 2416640;      // 256*128
constexpr int O_LW2 = 2449408;      // 128*256
constexpr int O_LW3 = 2482176;      // 64*128
constexpr int N_WBF = 2490368;

// ---------------------------------------------------------------------------
// One-time fp32 -> bf16 weight conversion into workspace
// ---------------------------------------------------------------------------
__global__ __launch_bounds__(256)
void k_prep(const float* __restrict__ wih, const float* __restrict__ aw1,
            const float* __restrict__ e1, const float* __restrict__ e2,
            const float* __restrict__ mw, const float* __restrict__ l1,
            const float* __restrict__ l2, const float* __restrict__ l3,
            u16* __restrict__ wbf) {
  int i = blockIdx.x * 256 + threadIdx.x;
  if (i >= N_WBF) return;
  float v;
  if (i < O_AW1)      v = wih[i];
  else if (i < O_EM1) v = aw1[i - O_AW1];
  else if (i < O_EM2) v = e1[i - O_EM1];
  else if (i < O_MLP) v = e2[i - O_EM2];
  else if (i < O_LW1) v = mw[i - O_MLP];
  else if (i < O_LW2) v = l1[i - O_LW1];
  else if (i < O_LW3) v = l2[i - O_LW2];
  else                v = l3[i - O_LW3];
  wbf[i] = f2bf(v);
}

// ---------------------------------------------------------------------------
// Whh fp32 -> i8 (scale 1016 = 127/0.125; |w|max ~0.097, no clipping)
// ---------------------------------------------------------------------------
__global__ __launch_bounds__(256)
void k_prepw(const float* __restrict__ whh, signed char* __restrict__ wq) {
  int i = blockIdx.x * 256 + threadIdx.x;   // 1,048,576 total
  float v = whh[i] * 1016.f;
  v = fminf(fmaxf(v, -127.f), 127.f);
  wq[i] = (signed char)(int)rintf(v);
}

// ---------------------------------------------------------------------------
// xg = X @ Wih_l^T + bih + bhh   via MFMA.  grid (256 rowblk, 8 nchunk)
// ---------------------------------------------------------------------------
__global__ __launch_bounds__(256)
void k_xg_mfma(const float* __restrict__ X, const u16* __restrict__ Wbf,
               const float* __restrict__ bi, const float* __restrict__ bh,
               float* __restrict__ xg) {
  __shared__ __align__(16) u16 sx[32 * 520];
  int tid = threadIdx.x;
  int rowbase = blockIdx.x * 32;
  int nchunk = blockIdx.y;
  for (int idx = tid; idx < 4096; idx += 256) {
    int r = idx >> 7, k4 = idx & 127;
    float4 v = *(const float4*)(X + (size_t)(rowbase + r) * 512 + k4 * 4);
    u32* p = (u32*)(sx + r * 520 + k4 * 4);
    p[0] = (u32)f2bf(v.x) | ((u32)f2bf(v.y) << 16);
    p[1] = (u32)f2bf(v.z) | ((u32)f2bf(v.w) << 16);
  }
  __syncthreads();
  int w = tid >> 6, lane = tid & 63;
  int msub = w >> 1, nhalf = w & 1;
  int mbase = msub * 16;
  int nb0 = nchunk * 256 + nhalf * 128;
  f32x4 acc[8];
#pragma unroll
  for (int i = 0; i < 8; ++i) acc[i] = f32x4{0.f, 0.f, 0.f, 0.f};
  for (int kt = 0; kt < 16; ++kt) {
    short8 a = *(const short8*)(sx + (mbase + (lane & 15)) * 520 + kt * 32 + (lane >> 4) * 8);
#pragma unroll
    for (int nt = 0; nt < 8; ++nt) {
      short8 b = *(const short8*)(Wbf + (size_t)(nb0 + nt * 16 + (lane & 15)) * 512 +
                                  kt * 32 + (lane >> 4) * 8);
      acc[nt] = __builtin_amdgcn_mfma_f32_16x16x32_bf16(a, b, acc[nt], 0, 0, 0);
    }
  }
  int mr = mbase + (lane >> 4) * 4;
#pragma unroll
  for (int nt = 0; nt < 8; ++nt) {
    int n = nb0 + nt * 16 + (lane & 15);
    float bb = bi[n] + bh[n];
#pragma unroll
    for (int r = 0; r < 4; ++r)
      xg[(size_t)(rowbase + mr + r) * 2048 + n] = acc[nt][r] + bb;
  }
}

// ---------------------------------------------------------------------------
// MFMA LSTM v7: batch-split, ZERO inter-block sync. 8 blocks = [d:2][bg:4],
// 512 threads. Full-direction Whh i8 in registers (32 frags = 128 VGPR).
// h in block-local LDS (i8, 272B row stride), one barrier per step.
// ---------------------------------------------------------------------------
__global__ __launch_bounds__(512, 1)
void k_lstm6(const float* __restrict__ xg, const signed char* __restrict__ wq,
             const int* __restrict__ lens, float* __restrict__ out, int layer) {
  __shared__ __align__(16) signed char hq[2][16 * 272];
  const int d = blockIdx.x >> 2, bg = blockIdx.x & 3;
  const int tid = threadIdx.x;
  const int jc = tid >> 6, l = tid & 63, ln = l & 15, lk = l >> 4;
  const int mb = bg * 16;

  // ---- weights: full direction, i8, register-resident ----
  i32x4 Bq[4][2][4];
  const signed char* wbase = wq + (size_t)(layer * 2 + d) * 262144;
#pragma unroll
  for (int g = 0; g < 4; ++g)
#pragma unroll
    for (int js = 0; js < 2; ++js)
#pragma unroll
      for (int kc = 0; kc < 4; ++kc) {
        int n = g * 256 + jc * 32 + js * 16 + ln;
        Bq[g][js][kc] = *(const i32x4*)(wbase + (size_t)n * 256 + kc * 64 + lk * 16);
      }

  int mlen[4];
#pragma unroll
  for (int r = 0; r < 4; ++r) mlen[r] = lens[mb + lk * 4 + r];

  float cst[2][4], hst[2][4];
#pragma unroll
  for (int js = 0; js < 2; ++js)
#pragma unroll
    for (int r = 0; r < 4; ++r) { cst[js][r] = 0.f; hst[js][r] = 0.f; }

  const float DEQ = 1.f / (1016.f * 127.f);

  for (int s = 0; s < 128; ++s) {
    const int t = d ? (127 - s) : s;

    // xg pre-activations: issued first, consumed after MFMA (latency hidden)
    float xv[4][2][4];
#pragma unroll
    for (int g = 0; g < 4; ++g)
#pragma unroll
      for (int js = 0; js < 2; ++js)
#pragma unroll
        for (int r = 0; r < 4; ++r)
          xv[g][js][r] = xg[((size_t)(mb + lk * 4 + r) * 128 + t) * 2048 +
                            d * 1024 + g * 256 + jc * 32 + js * 16 + ln];

    i32x4 acc[4][2];
#pragma unroll
    for (int g = 0; g < 4; ++g)
#pragma unroll
      for (int js = 0; js < 2; ++js) acc[g][js] = i32x4{0, 0, 0, 0};

    if (s > 0) {
      const signed char* hr = hq[(s & 1) ^ 1];
#pragma unroll
      for (int kc = 0; kc < 4; ++kc) {
        i32x4 a = *(const i32x4*)(hr + ln * 272 + kc * 64 + lk * 16);
#pragma unroll
        for (int g = 0; g < 4; ++g)
#pragma unroll
          for (int js = 0; js < 2; ++js)
            acc[g][js] = __builtin_amdgcn_mfma_i32_16x16x64_i8(a, Bq[g][js][kc],
                                                               acc[g][js], 0, 0, 0);
      }
    }

    signed char* hw = hq[s & 1];
#pragma unroll
    for (int js = 0; js < 2; ++js)
#pragma unroll
      for (int r = 0; r < 4; ++r) {
        float gi = (float)acc[0][js][r] * DEQ + xv[0][js][r];
        float gf = (float)acc[1][js][r] * DEQ + xv[1][js][r];
        float gg = (float)acc[2][js][r] * DEQ + xv[2][js][r];
        float go = (float)acc[3][js][r] * DEQ + xv[3][js][r];
        float c2 = sigf(gf) * cst[js][r] + sigf(gi) * tanh2(gg);
        float h2 = sigf(go) * tanh2(c2);
        const int m = lk * 4 + r;
        bool upd = t < mlen[r];
        cst[js][r] = upd ? c2 : cst[js][r];
        float hn = upd ? h2 : hst[js][r];
        hst[js][r] = hn;
        const int j = jc * 32 + js * 16 + ln;
        out[((size_t)(mb + m) * 128 + t) * 512 + d * 256 + j] = hn;
        hw[m * 272 + j] = (signed char)(int)rintf(hn * 127.f);
      }
    __syncthreads();
  }
}

// ---------------------------------------------------------------------------
// attn scores via MFMA: sc[m] = w2 . tanh(W1 @ rnn[m] + b1)
// ---------------------------------------------------------------------------
__global__ __launch_bounds__(256)
void k_attn(const float* __restrict__ rnn, const u16* __restrict__ W1bf,
            const float* __restrict__ b1, const float* __restrict__ w2,
            float* __restrict__ sc) {
  __shared__ __align__(16) u16 sx[32 * 520];
  __shared__ float sred[32];
  int tid = threadIdx.x;
  int rowbase = blockIdx.x * 32;
  for (int idx = tid; idx < 4096; idx += 256) {
    int r = idx >> 7, k4 = idx & 127;
    float4 v = *(const float4*)(rnn + (size_t)(rowbase + r) * 512 + k4 * 4);
    u32* p = (u32*)(sx + r * 520 + k4 * 4);
    p[0] = (u32)f2bf(v.x) | ((u32)f2bf(v.y) << 16);
    p[1] = (u32)f2bf(v.z) | ((u32)f2bf(v.w) << 16);
  }
  if (tid < 32) sred[tid] = 0.f;
  __syncthreads();
  int w = tid >> 6, lane = tid & 63;
  int msub = w >> 1, nhalf = w & 1;
  int mbase = msub * 16;
  float psum[4] = {0.f, 0.f, 0.f, 0.f};
  for (int ng = 0; ng < 4; ++ng) {
    f32x4 acc[4];
#pragma unroll
    for (int i = 0; i < 4; ++i) acc[i] = f32x4{0.f, 0.f, 0.f, 0.f};
    for (int kt = 0; kt < 16; ++kt) {
      short8 a = *(const short8*)(sx + (mbase + (lane & 15)) * 520 + kt * 32 + (lane >> 4) * 8);
#pragma unroll
      for (int nt = 0; nt < 4; ++nt) {
        int nrow = nhalf * 256 + ng * 64 + nt * 16 + (lane & 15);
        short8 b = *(const short8*)(W1bf + (size_t)nrow * 512 + kt * 32 + (lane >> 4) * 8);
        acc[nt] = __builtin_amdgcn_mfma_f32_16x16x32_bf16(a, b, acc[nt], 0, 0, 0);
      }
    }
#pragma unroll
    for (int nt = 0; nt < 4; ++nt) {
      int n = nhalf * 256 + ng * 64 + nt * 16 + (lane & 15);
      float wn = w2[n], bn = b1[n];
#pragma unroll
      for (int r = 0; r < 4; ++r) psum[r] += wn * tanh2(acc[nt][r] + bn);
    }
  }
#pragma unroll
  for (int off = 8; off >= 1; off >>= 1)
#pragma unroll
    for (int r = 0; r < 4; ++r) psum[r] += __shfl_xor(psum[r], off);
  if ((lane & 15) == 0) {
#pragma unroll
    for (int r = 0; r < 4; ++r)
      atomicAdd(&sred[msub * 16 + (lane >> 4) * 4 + r], psum[r]);
  }
  __syncthreads();
  if (tid < 32) sc[rowbase + tid] = sred[tid];
}

// ---------------------------------------------------------------------------
// Causal softmax + weighted sum as prefix scan. grid (64 b, 4 hchunk) x 128.
// ---------------------------------------------------------------------------
__global__ __launch_bounds__(128)
void k_ctx(const float* __restrict__ sc, const float* __restrict__ rnn,
           const int* __restrict__ lens, float* __restrict__ ctx) {
  int b = blockIdx.x;
  int h = blockIdx.y * 128 + threadIdx.x;
  __shared__ float ex[T];
  ex[threadIdx.x] = expf(sc[b * T + threadIdx.x]);
  __syncthreads();
  int len = lens[b];
  float acc = 0.f, den = 0.f;
  for (int t = 0; t < T; ++t) {
    float wv = ex[t];
    den += wv;
    acc += wv * rnn[((size_t)b * T + t) * 512 + h];
    ctx[((size_t)b * T + t) * 512 + h] = (t < len) ? (acc / den) : 0.f;
  }
}

// ---------------------------------------------------------------------------
// MFMA MLP stage on a 32-row bf16 LDS tile
// ---------------------------------------------------------------------------
template <int NT, int KT, bool RELU>
__device__ __forceinline__ void stage_mfma(const u16* __restrict__ Wbf,
                                           const float* __restrict__ bias,
                                           const u16* A, int lda,
                                           u16* O, int ldo, int nofs,
                                           int lane, int msub, int nhalf) {
  f32x4 acc[NT];
#pragma unroll
  for (int i = 0; i < NT; ++i) acc[i] = f32x4{0.f, 0.f, 0.f, 0.f};
  int mbase = msub * 16;
  int nb0 = nhalf * (NT * 16);
#pragma unroll
  for (int kt = 0; kt < KT; ++kt) {
    short8 a = *(const short8*)(A + (mbase + (lane & 15)) * lda + kt * 32 + (lane >> 4) * 8);
#pragma unroll
    for (int nt = 0; nt < NT; ++nt) {
      short8 b = *(const short8*)(Wbf + (size_t)(nb0 + nt * 16 + (lane & 15)) * (KT * 32) +
                                  kt * 32 + (lane >> 4) * 8);
      acc[nt] = __builtin_amdgcn_mfma_f32_16x16x32_bf16(a, b, acc[nt], 0, 0, 0);
    }
  }
  int mr = mbase + (lane >> 4) * 4;
#pragma unroll
  for (int nt = 0; nt < NT; ++nt) {
    int nl = nb0 + nt * 16 + (lane & 15);
    float bv = bias[nl];
#pragma unroll
    for (int r = 0; r < 4; ++r) {
      float v = acc[nt][r] + bv;
      if (RELU) v = fmaxf(v, 0.f);
      O[(mr + r) * ldo + nofs + nl] = f2bf(v);
    }
  }
}

// ---------------------------------------------------------------------------
// Fused sample branch, MFMA everywhere. 32 rows/block, 4096 blocks.
// ---------------------------------------------------------------------------
__global__ __launch_bounds__(256)
void k_sample(const float* __restrict__ ctx, const float* __restrict__ d2v,
              const float* __restrict__ user_table, const float* __restrict__ art_table,
              const int* __restrict__ user_ids, const int* __restrict__ sample_ids,
              const u16* __restrict__ wbf,
              const float* __restrict__ em_b1, const float* __restrict__ em_b2,
              const float* __restrict__ mlp_b,
              const float* __restrict__ lm_b1, const float* __restrict__ lm_b2,
              const float* __restrict__ lm_b3,
              const float* __restrict__ lm_W4, const float* __restrict__ lm_b4,
              float* __restrict__ out) {
  __shared__ __align__(16) u16 bufA[32 * 520];
  __shared__ __align__(16) u16 bufB[32 * 264];
  __shared__ __align__(16) u16 bufC[32 * 136];
  int tid = threadIdx.x, lane = tid & 63, w = tid >> 6;
  int msub = w >> 1, nhalf = w & 1;
  int rowbase = blockIdx.x * 32;

  for (int idx = tid; idx < 1024; idx += 256) {
    int r = idx >> 5, k4 = idx & 31;
    int m = rowbase + r;
    int sid = sample_ids[m];
    int uid = user_ids[m >> 11];
    float4 u = *(const float4*)(user_table + (size_t)uid * 128 + k4 * 4);
    float4 a = *(const float4*)(art_table + (size_t)sid * 128 + k4 * 4);
    u32* p = (u32*)(bufA + r * 520 + k4 * 4);
    p[0] = (u32)f2bf(u.x * a.x) | ((u32)f2bf(u.y * a.y) << 16);
    p[1] = (u32)f2bf(u.z * a.z) | ((u32)f2bf(u.w * a.w) << 16);
  }
  __syncthreads();
  stage_mfma<4, 4, true>(wbf + O_EM1, em_b1, bufA, 520, bufB, 264, 0, lane, msub, nhalf);
  __syncthreads();
  stage_mfma<2, 4, true>(wbf + O_EM2, em_b2, bufB, 264, bufC, 136, 0, lane, msub, nhalf);
  for (int idx = tid; idx < 4096; idx += 256) {
    int r = idx >> 7, k4 = idx & 127;
    int m = rowbase + r;
    int bt = m >> 4;
    float4 cx = *(const float4*)(ctx + (size_t)bt * 512 + k4 * 4);
    float4 dv = *(const float4*)(d2v + (size_t)m * 512 + k4 * 4);
    u32* p = (u32*)(bufA + r * 520 + k4 * 4);
    p[0] = (u32)f2bf(cx.x * dv.x) | ((u32)f2bf(cx.y * dv.y) << 16);
    p[1] = (u32)f2bf(cx.z * dv.z) | ((u32)f2bf(cx.w * dv.w) << 16);
  }
  __syncthreads();
  stage_mfma<2, 16, false>(wbf + O_MLP, mlp_b, bufA, 520, bufC, 136, 64, lane, msub, nhalf);
  __syncthreads();
  stage_mfma<8, 4, true>(wbf + O_LW1, lm_b1, bufC, 136, bufB, 264, 0, lane, msub, nhalf);
  __syncthreads();
  stage_mfma<4, 8, true>(wbf + O_LW2, lm_b2, bufB, 264, bufA, 520, 0, lane, msub, nhalf);
  __syncthreads();
  stage_mfma<2, 4, true>(wbf + O_LW3, lm_b3, bufA, 520, bufC, 136, 0, lane, msub, nhalf);
  __syncthreads();

  if (tid < 32) {
    float acc = lm_b4[0];
#pragma unroll
    for (int k = 0; k < 64; ++k) acc += bf2f(bufC[tid * 136 + k]) * lm_W4[k];
    out[rowbase + tid] = sigf(acc);
  }
}

}  // namespace

extern "C" void kernel_launch(void* const* d_in, const int* in_sizes, int n_in,
                              void* d_out, int out_size, void* d_ws, size_t ws_size,
                              hipStream_t stream) {
  const float* x1   = (const float*)d_in[0];
  const float* d2v  = (const float*)d_in[1];
  const float* Wih  = (const float*)d_in[2];
  const float* Whh  = (const float*)d_in[3];
  const float* bih  = (const float*)d_in[4];
  const float* bhh  = (const float*)d_in[5];
  const float* aW1  = (const float*)d_in[6];
  const float* ab1  = (const float*)d_in[7];
  const float* aw2  = (const float*)d_in[8];
  const float* mlpW = (const float*)d_in[9];
  const float* mlpb = (const float*)d_in[10];
  const float* utab = (const float*)d_in[11];
  const float* atab = (const float*)d_in[12];
  const float* emW1 = (const float*)d_in[13];
  const float* emb1 = (const float*)d_in[14];
  const float* emW2 = (const float*)d_in[15];
  const float* emb2 = (const float*)d_in[16];
  const float* lmW1 = (const float*)d_in[17];
  const float* lmb1 = (const float*)d_in[18];
  const float* lmW2 = (const float*)d_in[19];
  const float* lmb2 = (const float*)d_in[20];
  const float* lmW3 = (const float*)d_in[21];
  const float* lmb3 = (const float*)d_in[22];
  const float* lmW4 = (const float*)d_in[23];
  const float* lmb4 = (const float*)d_in[24];
  const int* lens   = (const int*)d_in[27];
  const int* uids   = (const int*)d_in[28];
  const int* sids   = (const int*)d_in[29];
  float* out = (float*)d_out;

  float* ws = (float*)d_ws;
  // float-unit offsets
  signed char* WQ = (signed char*)ws;                  // 1 MB i8 [0, 262144)
  float* SC  = ws + 262144;                            // 8192
  u16* WBF = (u16*)(ws + 270336);                      // 2,490,368 u16
  float* XG  = ws + 1515520;                           // 16,777,216 f32
  float* R0  = ws + 18292736;                          // 4,194,304
  float* R1  = ws + 22487040;                          // 4,194,304
  float* CTX = ws + 18292736;                          // overlays R0 (R0 dead
                                                       // before k_ctx writes)

  k_prep<<<(N_WBF + 255) / 256, 256, 0, stream>>>(Wih, aW1, emW1, emW2, mlpW,
                                                  lmW1, lmW2, lmW3, WBF);
  k_prepw<<<4096, 256, 0, stream>>>(Whh, WQ);
  k_xg_mfma<<<dim3(256, 8), 256, 0, stream>>>(x1, WBF + O_WIH, bih, bhh, XG);
  k_lstm6<<<8, 512, 0, stream>>>(XG, WQ, lens, R0, 0);
  k_xg_mfma<<<dim3(256, 8), 256, 0, stream>>>(R0, WBF + O_WIH + 1048576,
                                              bih + 2048, bhh + 2048, XG);
  k_lstm6<<<8, 512, 0, stream>>>(XG, WQ, lens, R1, 1);
  k_attn<<<256, 256, 0, stream>>>(R1, WBF + O_AW1, ab1, aw2, SC);
  k_ctx<<<dim3(64, 4), 128, 0, stream>>>(SC, R1, lens, CTX);
  k_sample<<<4096, 256, 0, stream>>>(CTX, d2v, utab, atab, uids, sids, WBF,
                                     emb1, emb2, mlpb, lmb1, lmb2, lmb3,
                                     lmW4, lmb4, out);
}

// Round 11
// 1259.706 us; speedup vs baseline: 1.5585x; 1.0060x over previous
//
#include <hip/hip_runtime.h>
#include <cstddef>

namespace {

constexpr int T = 128;

typedef unsigned short u16;
typedef unsigned int u32;
typedef __attribute__((ext_vector_type(8))) short short8;
typedef __attribute__((ext_vector_type(4))) float f32x4;
typedef __attribute__((ext_vector_type(4))) int i32x4;

__device__ __forceinline__ u16 f2bf(float x) {
  u32 u = __float_as_uint(x);
  u = (u + 0x7FFFu + ((u >> 16) & 1u)) >> 16;
  return (u16)u;
}
__device__ __forceinline__ float bf2f(u16 v) {
  return __uint_as_float(((u32)v) << 16);
}
// exp2/rcp-based activations: single v_exp_f32 / v_rcp_f32, branch-free.
__device__ __forceinline__ float sigf(float x) {
  return __builtin_amdgcn_rcpf(1.f + __builtin_amdgcn_exp2f(-1.44269504f * x));
}
__device__ __forceinline__ float tanh2(float x) {
  return 1.f - 2.f * __builtin_amdgcn_rcpf(1.f + __builtin_amdgcn_exp2f(2.88539008f * x));
}
// Barrier that drains ONLY LDS ops (lgkmcnt) — __syncthreads would also wait
// vmcnt(0), serializing on HBM store-acks that nothing after depends on.
__device__ __forceinline__ void bar_lds() {
  asm volatile("s_waitcnt lgkmcnt(0)\n\ts_barrier" ::: "memory");
}

// ---- WBF sub-offsets (ushort units) ----
constexpr int O_WIH = 0;            // 2*2048*512
constexpr int O_AW1 = 2097152;      // 512*512
constexpr int O_EM1 = 2359296;      // 128*128
constexpr int O_EM2 = 2375680;      // 64*128
constexpr int O_MLP = 2383872;      // 64*512
constexpr int O_LW1 = 2416640;      // 256*128
constexpr int O_LW2 = 2449408;      // 128*256
constexpr int O_LW3 = 2482176;      // 64*128
constexpr int N_WBF = 2490368;

// ---------------------------------------------------------------------------
// One-time fp32 -> bf16 weight conversion into workspace
// ---------------------------------------------------------------------------
__global__ __launch_bounds__(256)
void k_prep(const float* __restrict__ wih, const float* __restrict__ aw1,
            const float* __restrict__ e1, const float* __restrict__ e2,
            const float* __restrict__ mw, const float* __restrict__ l1,
            const float* __restrict__ l2, const float* __restrict__ l3,
            u16* __restrict__ wbf) {
  int i = blockIdx.x * 256 + threadIdx.x;
  if (i >= N_WBF) return;
  float v;
  if (i < O_AW1)      v = wih[i];
  else if (i < O_EM1) v = aw1[i - O_AW1];
  else if (i < O_EM2) v = e1[i - O_EM1];
  else if (i < O_MLP) v = e2[i - O_EM2];
  else if (i < O_LW1) v = mw[i - O_MLP];
  else if (i < O_LW2) v = l1[i - O_LW1];
  else if (i < O_LW3) v = l2[i - O_LW2];
  else                v = l3[i - O_LW3];
  wbf[i] = f2bf(v);
}

// ---------------------------------------------------------------------------
// Whh fp32 -> i8 (scale 1016 = 127/0.125; |w|max ~0.097, no clipping)
// ---------------------------------------------------------------------------
__global__ __launch_bounds__(256)
void k_prepw(const float* __restrict__ whh, signed char* __restrict__ wq) {
  int i = blockIdx.x * 256 + threadIdx.x;   // 1,048,576 total
  float v = whh[i] * 1016.f;
  v = fminf(fmaxf(v, -127.f), 127.f);
  wq[i] = (signed char)(int)rintf(v);
}

// ---------------------------------------------------------------------------
// xg = X @ Wih_l^T + bih + bhh   via MFMA.  grid (256 rowblk, 8 nchunk)
// ---------------------------------------------------------------------------
__global__ __launch_bounds__(256)
void k_xg_mfma(const float* __restrict__ X, const u16* __restrict__ Wbf,
               const float* __restrict__ bi, const float* __restrict__ bh,
               float* __restrict__ xg) {
  __shared__ __align__(16) u16 sx[32 * 520];
  int tid = threadIdx.x;
  int rowbase = blockIdx.x * 32;
  int nchunk = blockIdx.y;
  for (int idx = tid; idx < 4096; idx += 256) {
    int r = idx >> 7, k4 = idx & 127;
    float4 v = *(const float4*)(X + (size_t)(rowbase + r) * 512 + k4 * 4);
    u32* p = (u32*)(sx + r * 520 + k4 * 4);
    p[0] = (u32)f2bf(v.x) | ((u32)f2bf(v.y) << 16);
    p[1] = (u32)f2bf(v.z) | ((u32)f2bf(v.w) << 16);
  }
  __syncthreads();
  int w = tid >> 6, lane = tid & 63;
  int msub = w >> 1, nhalf = w & 1;
  int mbase = msub * 16;
  int nb0 = nchunk * 256 + nhalf * 128;
  f32x4 acc[8];
#pragma unroll
  for (int i = 0; i < 8; ++i) acc[i] = f32x4{0.f, 0.f, 0.f, 0.f};
  for (int kt = 0; kt < 16; ++kt) {
    short8 a = *(const short8*)(sx + (mbase + (lane & 15)) * 520 + kt * 32 + (lane >> 4) * 8);
#pragma unroll
    for (int nt = 0; nt < 8; ++nt) {
      short8 b = *(const short8*)(Wbf + (size_t)(nb0 + nt * 16 + (lane & 15)) * 512 +
                                  kt * 32 + (lane >> 4) * 8);
      acc[nt] = __builtin_amdgcn_mfma_f32_16x16x32_bf16(a, b, acc[nt], 0, 0, 0);
    }
  }
  int mr = mbase + (lane >> 4) * 4;
#pragma unroll
  for (int nt = 0; nt < 8; ++nt) {
    int n = nb0 + nt * 16 + (lane & 15);
    float bb = bi[n] + bh[n];
#pragma unroll
    for (int r = 0; r < 4; ++r)
      xg[(size_t)(rowbase + mr + r) * 2048 + n] = acc[nt][r] + bb;
  }
}

// ---------------------------------------------------------------------------
// MFMA LSTM v7: batch-split, ZERO inter-block sync. 8 blocks = [d:2][bg:4],
// 512 threads. Full-direction Whh i8 in registers. h in block-local LDS.
// Per-step barrier drains lgkmcnt only (out[] HBM acks never waited).
// ---------------------------------------------------------------------------
__global__ __launch_bounds__(512, 1)
void k_lstm6(const float* __restrict__ xg, const signed char* __restrict__ wq,
             const int* __restrict__ lens, float* __restrict__ out, int layer) {
  __shared__ __align__(16) signed char hq[2][16 * 272];
  const int d = blockIdx.x >> 2, bg = blockIdx.x & 3;
  const int tid = threadIdx.x;
  const int jc = tid >> 6, l = tid & 63, ln = l & 15, lk = l >> 4;
  const int mb = bg * 16;

  // ---- weights: full direction, i8, register-resident ----
  i32x4 Bq[4][2][4];
  const signed char* wbase = wq + (size_t)(layer * 2 + d) * 262144;
#pragma unroll
  for (int g = 0; g < 4; ++g)
#pragma unroll
    for (int js = 0; js < 2; ++js)
#pragma unroll
      for (int kc = 0; kc < 4; ++kc) {
        int n = g * 256 + jc * 32 + js * 16 + ln;
        Bq[g][js][kc] = *(const i32x4*)(wbase + (size_t)n * 256 + kc * 64 + lk * 16);
      }

  int mlen[4];
#pragma unroll
  for (int r = 0; r < 4; ++r) mlen[r] = lens[mb + lk * 4 + r];

  float cst[2][4], hst[2][4];
#pragma unroll
  for (int js = 0; js < 2; ++js)
#pragma unroll
    for (int r = 0; r < 4; ++r) { cst[js][r] = 0.f; hst[js][r] = 0.f; }

  const float DEQ = 1.f / (1016.f * 127.f);

  for (int s = 0; s < 128; ++s) {
    const int t = d ? (127 - s) : s;

    // xg pre-activations: issued first, consumed at gates (after MFMA)
    float xv[4][2][4];
#pragma unroll
    for (int g = 0; g < 4; ++g)
#pragma unroll
      for (int js = 0; js < 2; ++js)
#pragma unroll
        for (int r = 0; r < 4; ++r)
          xv[g][js][r] = xg[((size_t)(mb + lk * 4 + r) * 128 + t) * 2048 +
                            d * 1024 + g * 256 + jc * 32 + js * 16 + ln];

    i32x4 acc[4][2];
#pragma unroll
    for (int g = 0; g < 4; ++g)
#pragma unroll
      for (int js = 0; js < 2; ++js) acc[g][js] = i32x4{0, 0, 0, 0};

    if (s > 0) {
      const signed char* hr = hq[(s & 1) ^ 1];
#pragma unroll
      for (int kc = 0; kc < 4; ++kc) {
        i32x4 a = *(const i32x4*)(hr + ln * 272 + kc * 64 + lk * 16);
#pragma unroll
        for (int g = 0; g < 4; ++g)
#pragma unroll
          for (int js = 0; js < 2; ++js)
            acc[g][js] = __builtin_amdgcn_mfma_i32_16x16x64_i8(a, Bq[g][js][kc],
                                                               acc[g][js], 0, 0, 0);
      }
    }

    signed char* hw = hq[s & 1];
#pragma unroll
    for (int js = 0; js < 2; ++js)
#pragma unroll
      for (int r = 0; r < 4; ++r) {
        float gi = (float)acc[0][js][r] * DEQ + xv[0][js][r];
        float gf = (float)acc[1][js][r] * DEQ + xv[1][js][r];
        float gg = (float)acc[2][js][r] * DEQ + xv[2][js][r];
        float go = (float)acc[3][js][r] * DEQ + xv[3][js][r];
        float c2 = sigf(gf) * cst[js][r] + sigf(gi) * tanh2(gg);
        float h2 = sigf(go) * tanh2(c2);
        const int m = lk * 4 + r;
        bool upd = t < mlen[r];
        cst[js][r] = upd ? c2 : cst[js][r];
        float hn = upd ? h2 : hst[js][r];
        hst[js][r] = hn;
        const int j = jc * 32 + js * 16 + ln;
        out[((size_t)(mb + m) * 128 + t) * 512 + d * 256 + j] = hn;
        hw[m * 272 + j] = (signed char)(int)rintf(hn * 127.f);
      }
    bar_lds();
  }
}

// ---------------------------------------------------------------------------
// attn scores via MFMA: sc[m] = w2 . tanh(W1 @ rnn[m] + b1)
// ---------------------------------------------------------------------------
__global__ __launch_bounds__(256)
void k_attn(const float* __restrict__ rnn, const u16* __restrict__ W1bf,
            const float* __restrict__ b1, const float* __restrict__ w2,
            float* __restrict__ sc) {
  __shared__ __align__(16) u16 sx[32 * 520];
  __shared__ float sred[32];
  int tid = threadIdx.x;
  int rowbase = blockIdx.x * 32;
  for (int idx = tid; idx < 4096; idx += 256) {
    int r = idx >> 7, k4 = idx & 127;
    float4 v = *(const float4*)(rnn + (size_t)(rowbase + r) * 512 + k4 * 4);
    u32* p = (u32*)(sx + r * 520 + k4 * 4);
    p[0] = (u32)f2bf(v.x) | ((u32)f2bf(v.y) << 16);
    p[1] = (u32)f2bf(v.z) | ((u32)f2bf(v.w) << 16);
  }
  if (tid < 32) sred[tid] = 0.f;
  __syncthreads();
  int w = tid >> 6, lane = tid & 63;
  int msub = w >> 1, nhalf = w & 1;
  int mbase = msub * 16;
  float psum[4] = {0.f, 0.f, 0.f, 0.f};
  for (int ng = 0; ng < 4; ++ng) {
    f32x4 acc[4];
#pragma unroll
    for (int i = 0; i < 4; ++i) acc[i] = f32x4{0.f, 0.f, 0.f, 0.f};
    for (int kt = 0; kt < 16; ++kt) {
      short8 a = *(const short8*)(sx + (mbase + (lane & 15)) * 520 + kt * 32 + (lane >> 4) * 8);
#pragma unroll
      for (int nt = 0; nt < 4; ++nt) {
        int nrow = nhalf * 256 + ng * 64 + nt * 16 + (lane & 15);
        short8 b = *(const short8*)(W1bf + (size_t)nrow * 512 + kt * 32 + (lane >> 4) * 8);
        acc[nt] = __builtin_amdgcn_mfma_f32_16x16x32_bf16(a, b, acc[nt], 0, 0, 0);
      }
    }
#pragma unroll
    for (int nt = 0; nt < 4; ++nt) {
      int n = nhalf * 256 + ng * 64 + nt * 16 + (lane & 15);
      float wn = w2[n], bn = b1[n];
#pragma unroll
      for (int r = 0; r < 4; ++r) psum[r] += wn * tanh2(acc[nt][r] + bn);
    }
  }
#pragma unroll
  for (int off = 8; off >= 1; off >>= 1)
#pragma unroll
    for (int r = 0; r < 4; ++r) psum[r] += __shfl_xor(psum[r], off);
  if ((lane & 15) == 0) {
#pragma unroll
    for (int r = 0; r < 4; ++r)
      atomicAdd(&sred[msub * 16 + (lane >> 4) * 4 + r], psum[r]);
  }
  __syncthreads();
  if (tid < 32) sc[rowbase + tid] = sred[tid];
}

// ---------------------------------------------------------------------------
// Causal softmax + weighted sum as prefix scan. grid (64 b, 4 hchunk) x 128.
// ---------------------------------------------------------------------------
__global__ __launch_bounds__(128)
void k_ctx(const float* __restrict__ sc, const float* __restrict__ rnn,
           const int* __restrict__ lens, float* __restrict__ ctx) {
  int b = blockIdx.x;
  int h = blockIdx.y * 128 + threadIdx.x;
  __shared__ float ex[T];
  ex[threadIdx.x] = expf(sc[b * T + threadIdx.x]);
  __syncthreads();
  int len = lens[b];
  float acc = 0.f, den = 0.f;
  for (int t = 0; t < T; ++t) {
    float wv = ex[t];
    den += wv;
    acc += wv * rnn[((size_t)b * T + t) * 512 + h];
    ctx[((size_t)b * T + t) * 512 + h] = (t < len) ? (acc / den) : 0.f;
  }
}

// ---------------------------------------------------------------------------
// MFMA MLP stage on a 32-row bf16 LDS tile
// ---------------------------------------------------------------------------
template <int NT, int KT, bool RELU>
__device__ __forceinline__ void stage_mfma(const u16* __restrict__ Wbf,
                                           const float* __restrict__ bias,
                                           const u16* A, int lda,
                                           u16* O, int ldo, int nofs,
                                           int lane, int msub, int nhalf) {
  f32x4 acc[NT];
#pragma unroll
  for (int i = 0; i < NT; ++i) acc[i] = f32x4{0.f, 0.f, 0.f, 0.f};
  int mbase = msub * 16;
  int nb0 = nhalf * (NT * 16);
#pragma unroll
  for (int kt = 0; kt < KT; ++kt) {
    short8 a = *(const short8*)(A + (mbase + (lane & 15)) * lda + kt * 32 + (lane >> 4) * 8);
#pragma unroll
    for (int nt = 0; nt < NT; ++nt) {
      short8 b = *(const short8*)(Wbf + (size_t)(nb0 + nt * 16 + (lane & 15)) * (KT * 32) +
                                  kt * 32 + (lane >> 4) * 8);
      acc[nt] = __builtin_amdgcn_mfma_f32_16x16x32_bf16(a, b, acc[nt], 0, 0, 0);
    }
  }
  int mr = mbase + (lane >> 4) * 4;
#pragma unroll
  for (int nt = 0; nt < NT; ++nt) {
    int nl = nb0 + nt * 16 + (lane & 15);
    float bv = bias[nl];
#pragma unroll
    for (int r = 0; r < 4; ++r) {
      float v = acc[nt][r] + bv;
      if (RELU) v = fmaxf(v, 0.f);
      O[(mr + r) * ldo + nofs + nl] = f2bf(v);
    }
  }
}

// ---------------------------------------------------------------------------
// Fused sample branch. 32 rows/block, 4096 blocks. LDS 42.6 KB -> 3 blk/CU.
// r-branch K=512 staged in 2x256 chunks; lw3+lw4 fused in-register.
// ---------------------------------------------------------------------------
__global__ __launch_bounds__(256)
void k_sample(const float* __restrict__ ctx, const float* __restrict__ d2v,
              const float* __restrict__ user_table, const float* __restrict__ art_table,
              const int* __restrict__ user_ids, const int* __restrict__ sample_ids,
              const u16* __restrict__ wbf,
              const float* __restrict__ em_b1, const float* __restrict__ em_b2,
              const float* __restrict__ mlp_b,
              const float* __restrict__ lm_b1, const float* __restrict__ lm_b2,
              const float* __restrict__ lm_b3,
              const float* __restrict__ lm_W4, const float* __restrict__ lm_b4,
              float* __restrict__ out) {
  __shared__ __align__(16) u16 bufA[32 * 264];
  __shared__ __align__(16) u16 bufB[32 * 264];
  __shared__ __align__(16) u16 bufC[32 * 136];
  __shared__ float sred[32];
  int tid = threadIdx.x, lane = tid & 63, w = tid >> 6;
  int msub = w >> 1, nhalf = w & 1;
  int mbase = msub * 16;
  int rowbase = blockIdx.x * 32;

  if (tid < 32) sred[tid] = 0.f;

  // e0 = user_emb * art_emb  -> bufA[:, 0:128]
  for (int idx = tid; idx < 1024; idx += 256) {
    int r = idx >> 5, k4 = idx & 31;
    int m = rowbase + r;
    int sid = sample_ids[m];
    int uid = user_ids[m >> 11];
    float4 u = *(const float4*)(user_table + (size_t)uid * 128 + k4 * 4);
    float4 a = *(const float4*)(art_table + (size_t)sid * 128 + k4 * 4);
    u32* p = (u32*)(bufA + r * 264 + k4 * 4);
    p[0] = (u32)f2bf(u.x * a.x) | ((u32)f2bf(u.y * a.y) << 16);
    p[1] = (u32)f2bf(u.z * a.z) | ((u32)f2bf(u.w * a.w) << 16);
  }
  bar_lds();
  stage_mfma<4, 4, true>(wbf + O_EM1, em_b1, bufA, 264, bufB, 264, 0, lane, msub, nhalf);
  bar_lds();
  // em2 (bufB->bufC) + r-chunk0 staging (->bufA) share the sync region
  stage_mfma<2, 4, true>(wbf + O_EM2, em_b2, bufB, 264, bufC, 136, 0, lane, msub, nhalf);
  for (int idx = tid; idx < 2048; idx += 256) {
    int r = idx >> 6, k4 = idx & 63;
    int m = rowbase + r;
    int bt = m >> 4;
    float4 cx = *(const float4*)(ctx + (size_t)bt * 512 + k4 * 4);
    float4 dv = *(const float4*)(d2v + (size_t)m * 512 + k4 * 4);
    u32* p = (u32*)(bufA + r * 264 + k4 * 4);
    p[0] = (u32)f2bf(cx.x * dv.x) | ((u32)f2bf(cx.y * dv.y) << 16);
    p[1] = (u32)f2bf(cx.z * dv.z) | ((u32)f2bf(cx.w * dv.w) << 16);
  }
  bar_lds();

  // r = (ctx*d2v) @ mlp_W^T : accumulate over 2 K-chunks of 256
  f32x4 racc[2];
  racc[0] = f32x4{0.f, 0.f, 0.f, 0.f};
  racc[1] = f32x4{0.f, 0.f, 0.f, 0.f};
  for (int kc = 0; kc < 2; ++kc) {
#pragma unroll
    for (int kt = 0; kt < 8; ++kt) {
      short8 a = *(const short8*)(bufA + (mbase + (lane & 15)) * 264 + kt * 32 + (lane >> 4) * 8);
#pragma unroll
      for (int nt = 0; nt < 2; ++nt) {
        int n = nhalf * 32 + nt * 16 + (lane & 15);
        short8 b = *(const short8*)(wbf + O_MLP + (size_t)n * 512 + kc * 256 +
                                    kt * 32 + (lane >> 4) * 8);
        racc[nt] = __builtin_amdgcn_mfma_f32_16x16x32_bf16(a, b, racc[nt], 0, 0, 0);
      }
    }
    bar_lds();                      // all waves done reading bufA chunk kc
    if (kc == 0) {
      for (int idx = tid; idx < 2048; idx += 256) {
        int r = idx >> 6, k4 = idx & 63;
        int m = rowbase + r;
        int bt = m >> 4;
        float4 cx = *(const float4*)(ctx + (size_t)bt * 512 + 256 + k4 * 4);
        float4 dv = *(const float4*)(d2v + (size_t)m * 512 + 256 + k4 * 4);
        u32* p = (u32*)(bufA + r * 264 + k4 * 4);
        p[0] = (u32)f2bf(cx.x * dv.x) | ((u32)f2bf(cx.y * dv.y) << 16);
        p[1] = (u32)f2bf(cx.z * dv.z) | ((u32)f2bf(cx.w * dv.w) << 16);
      }
      bar_lds();
    }
  }
  // racc -> bufC[:, 64:128]
  {
    int mr = mbase + (lane >> 4) * 4;
#pragma unroll
    for (int nt = 0; nt < 2; ++nt) {
      int nl = nhalf * 32 + nt * 16 + (lane & 15);
      float bv = mlp_b[nl];
#pragma unroll
      for (int r = 0; r < 4; ++r)
        bufC[(mr + r) * 136 + 64 + nl] = f2bf(racc[nt][r] + bv);
    }
  }
  bar_lds();
  stage_mfma<8, 4, true>(wbf + O_LW1, lm_b1, bufC, 136, bufB, 264, 0, lane, msub, nhalf);
  bar_lds();
  stage_mfma<4, 8, true>(wbf + O_LW2, lm_b2, bufB, 264, bufA, 264, 0, lane, msub, nhalf);
  bar_lds();

  // fused lw3 (relu) + lw4 dot: in-register, shfl reduce, one LDS atomic
  {
    f32x4 acc[2];
    acc[0] = f32x4{0.f, 0.f, 0.f, 0.f};
    acc[1] = f32x4{0.f, 0.f, 0.f, 0.f};
#pragma unroll
    for (int kt = 0; kt < 4; ++kt) {
      short8 a = *(const short8*)(bufA + (mbase + (lane & 15)) * 264 + kt * 32 + (lane >> 4) * 8);
#pragma unroll
      for (int nt = 0; nt < 2; ++nt) {
        int n = nhalf * 32 + nt * 16 + (lane & 15);
        short8 b = *(const short8*)(wbf + O_LW3 + (size_t)n * 128 +
                                    kt * 32 + (lane >> 4) * 8);
        acc[nt] = __builtin_amdgcn_mfma_f32_16x16x32_bf16(a, b, acc[nt], 0, 0, 0);
      }
    }
    float psum[4] = {0.f, 0.f, 0.f, 0.f};
#pragma unroll
    for (int nt = 0; nt < 2; ++nt) {
      int nl = nhalf * 32 + nt * 16 + (lane & 15);
      float bv = lm_b3[nl], w4 = lm_W4[nl];
#pragma unroll
      for (int r = 0; r < 4; ++r) psum[r] += w4 * fmaxf(acc[nt][r] + bv, 0.f);
    }
#pragma unroll
    for (int off = 8; off >= 1; off >>= 1)
#pragma unroll
      for (int r = 0; r < 4; ++r) psum[r] += __shfl_xor(psum[r], off);
    if ((lane & 15) == 0) {
#pragma unroll
      for (int r = 0; r < 4; ++r)
        atomicAdd(&sred[mbase + (lane >> 4) * 4 + r], psum[r]);
    }
  }
  bar_lds();
  if (tid < 32) out[rowbase + tid] = sigf(sred[tid] + lm_b4[0]);
}

}  // namespace

extern "C" void kernel_launch(void* const* d_in, const int* in_sizes, int n_in,
                              void* d_out, int out_size, void* d_ws, size_t ws_size,
                              hipStream_t stream) {
  const float* x1   = (const float*)d_in[0];
  const float* d2v  = (const float*)d_in[1];
  const float* Wih  = (const float*)d_in[2];
  const float* Whh  = (const float*)d_in[3];
  const float* bih  = (const float*)d_in[4];
  const float* bhh  = (const float*)d_in[5];
  const float* aW1  = (const float*)d_in[6];
  const float* ab1  = (const float*)d_in[7];
  const float* aw2  = (const float*)d_in[8];
  const float* mlpW = (const float*)d_in[9];
  const float* mlpb = (const float*)d_in[10];
  const float* utab = (const float*)d_in[11];
  const float* atab = (const float*)d_in[12];
  const float* emW1 = (const float*)d_in[13];
  const float* emb1 = (const float*)d_in[14];
  const float* emW2 = (const float*)d_in[15];
  const float* emb2 = (const float*)d_in[16];
  const float* lmW1 = (const float*)d_in[17];
  const float* lmb1 = (const float*)d_in[18];
  const float* lmW2 = (const float*)d_in[19];
  const float* lmb2 = (const float*)d_in[20];
  const float* lmW3 = (const float*)d_in[21];
  const float* lmb3 = (const float*)d_in[22];
  const float* lmW4 = (const float*)d_in[23];
  const float* lmb4 = (const float*)d_in[24];
  const int* lens   = (const int*)d_in[27];
  const int* uids   = (const int*)d_in[28];
  const int* sids   = (const int*)d_in[29];
  float* out = (float*)d_out;

  float* ws = (float*)d_ws;
  // float-unit offsets
  signed char* WQ = (signed char*)ws;                  // 1 MB i8 [0, 262144)
  float* SC  = ws + 262144;                            // 8192
  u16* WBF = (u16*)(ws + 270336);                      // 2,490,368 u16
  float* XG  = ws + 1515520;                           // 16,777,216 f32
  float* R0  = ws + 18292736;                          // 4,194,304
  float* R1  = ws + 22487040;                          // 4,194,304
  float* CTX = ws + 18292736;                          // overlays R0 (R0 dead
                                                       // before k_ctx writes)

  k_prep<<<(N_WBF + 255) / 256, 256, 0, stream>>>(Wih, aW1, emW1, emW2, mlpW,
                                                  lmW1, lmW2, lmW3, WBF);
  k_prepw<<<4096, 256, 0, stream>>>(Whh, WQ);
  k_xg_mfma<<<dim3(256, 8), 256, 0, stream>>>(x1, WBF + O_WIH, bih, bhh, XG);
  k_lstm6<<<8, 512, 0, stream>>>(XG, WQ, lens, R0, 0);
  k_xg_mfma<<<dim3(256, 8), 256, 0, stream>>>(R0, WBF + O_WIH + 1048576,
                                              bih + 2048, bhh + 2048, XG);
  k_lstm6<<<8, 512, 0, stream>>>(XG, WQ, lens, R1, 1);
  k_attn<<<256, 256, 0, stream>>>(R1, WBF + O_AW1, ab1, aw2, SC);
  k_ctx<<<dim3(64, 4), 128, 0, stream>>>(SC, R1, lens, CTX);
  k_sample<<<4096, 256, 0, stream>>>(CTX, d2v, utab, atab, uids, sids, WBF,
                                     emb1, emb2, mlpb, lmb1, lmb2, lmb3,
                                     lmW4, lmb4, out);
}